// Round 4
// baseline (76.765 us; speedup 1.0000x reference)
//
#include <hip/hip_runtime.h>
#include <math.h>

// PlaceCellNetwork: C=4, B=2048, IN=64, OUT=128, 100 fixed-point iterations.
//
// With M == I (the actual input, verified EXACTLY via bitwise check), the
// per-element iteration collapses in closed form (round-2 derivation):
//   y_final = max(P_100*wx + Q_100 - P_100*b, 0)   exactly,
// since the clamp-boundary ratio is monotone (dt non-increasing) and a
// clamped element stays clamped. P,Q computed on host in double.
//
// Round-4 restructure: kernel is issue-bound at depressed core clock
// (tiny dispatches never ramp; round-2/3 deltas imply ~550 MHz effective).
// -> 1024 blocks x 256 thr, 8 rows/block, 2 rows/wave: fma/thread halves
// (512 -> 256) and occupancy doubles (2 -> 4 blocks/CU, 16 waves/CU).

#define C_ 4
#define IN_ 64
#define OUT_ 128
#define B_ 2048
#define MAXITER_ 100
#define LBD1_ 0.005f
#define LBD2_ 0.005f

#define THREADS_ 256
#define ROWS_PER_BLOCK_ 8    // 4 waves x 2 rows
#define WT_PITCH_ 132        // conflict-free transpose writes; b64 reads at min aliasing

__global__ __launch_bounds__(THREADS_)
void pcn_kernel(const float* __restrict__ X,
                const float* __restrict__ W,
                const float* __restrict__ M,
                const float* __restrict__ bvec,
                float* __restrict__ out,
                float Pc, float Qc)
{
    __shared__ __align__(16) float smem[IN_ * WT_PITCH_];   // W^T; reused as Y (8x128) in general path
    __shared__ unsigned red[4];

    const int tid   = threadIdx.x;
    const int bx    = blockIdx.x;
    const int c     = bx >> 8;        // 256 chunks per c
    const int chunk = bx & 255;
    const int wv    = tid >> 6;       // wave 0..3
    const int lane  = tid & 63;
    const int p0    = 2 * lane;       // owned cols p0, p0+1

    const float* Wc = W + c * (OUT_ * IN_);
    const float* Mc = M + c * (OUT_ * OUT_);

    // ---- stage W^T into LDS: WT[i][o] = W[o][i] (2-way write alias = free) --
    {
        const int o    = tid >> 1;
        const int half = tid & 1;
        const float4* wrow = (const float4*)(Wc + o * IN_ + half * 32);
        #pragma unroll
        for (int j4 = 0; j4 < 8; ++j4) {
            float4 v = wrow[j4];
            int i0 = half * 32 + j4 * 4;
            smem[(i0 + 0) * WT_PITCH_ + o] = v.x;
            smem[(i0 + 1) * WT_PITCH_ + o] = v.y;
            smem[(i0 + 2) * WT_PITCH_ + o] = v.z;
            smem[(i0 + 3) * WT_PITCH_ + o] = v.w;
        }
    }

    // ---- bitwise M == I check over this thread's 64-entry segment ----------
    unsigned bad = 0;
    {
        const int row     = tid >> 1;
        const int colbase = (tid & 1) * 64;
        const int dIdx    = row - colbase;          // diagonal offset in segment (may be OOR)
        const uint4* mrow = (const uint4*)(Mc + row * OUT_ + colbase);
        #pragma unroll
        for (int j4 = 0; j4 < 16; ++j4) {
            uint4 v = mrow[j4];
            int e = dIdx - 4 * j4;
            bad |= v.x ^ ((e == 0) ? 0x3F800000u : 0u);
            bad |= v.y ^ ((e == 1) ? 0x3F800000u : 0u);
            bad |= v.z ^ ((e == 2) ? 0x3F800000u : 0u);
            bad |= v.w ^ ((e == 3) ? 0x3F800000u : 0u);
        }
    }

    const float2 bv2 = *(const float2*)(bvec + c * OUT_ + p0);

    __syncthreads();

    // ---- Wx: 2 rows x 2 cols per lane; X rows are wave-uniform -------------
    const int row0 = chunk * ROWS_PER_BLOCK_ + wv * 2;   // batch rows (within c)
    const float* xrow = X + __builtin_amdgcn_readfirstlane(row0 * IN_);

    float acc[2][2];
    acc[0][0] = 0.f; acc[0][1] = 0.f; acc[1][0] = 0.f; acc[1][1] = 0.f;

    #pragma unroll 4
    for (int i4 = 0; i4 < 16; ++i4) {
        float4 v0 = *(const float4*)(xrow + 0 * IN_ + 4 * i4);  // uniform -> s_load
        float4 v1 = *(const float4*)(xrow + 1 * IN_ + 4 * i4);
        float xq0[4] = {v0.x, v0.y, v0.z, v0.w};
        float xq1[4] = {v1.x, v1.y, v1.z, v1.w};
        #pragma unroll
        for (int di = 0; di < 4; ++di) {
            const int i = 4 * i4 + di;
            float2 w2 = *(const float2*)(smem + i * WT_PITCH_ + p0);
            acc[0][0] = fmaf(w2.x, xq0[di], acc[0][0]);
            acc[0][1] = fmaf(w2.y, xq0[di], acc[0][1]);
            acc[1][0] = fmaf(w2.x, xq1[di], acc[1][0]);
            acc[1][1] = fmaf(w2.y, xq1[di], acc[1][1]);
        }
    }

    // ---- reduce M check -> block flag ---------------------------------------
    #pragma unroll
    for (int off = 32; off > 0; off >>= 1)
        bad |= __shfl_down(bad, off);
    if (lane == 0) red[wv] = bad;
    __syncthreads();   // also fences WT reads before Ylds reuse (general path)
    const bool m_ident = ((red[0] | red[1] | red[2] | red[3]) == 0u);

    float y[2][2];

    if (m_ident) {
        // ---- closed form: y = max(P*wx + (Q - P*b), 0) ----------------------
        const float g0 = fmaf(-Pc, bv2.x, Qc);
        const float g1 = fmaf(-Pc, bv2.y, Qc);
        #pragma unroll
        for (int r = 0; r < 2; ++r) {
            y[r][0] = fmaxf(fmaf(Pc, acc[r][0], g0), 0.0f);
            y[r][1] = fmaxf(fmaf(Pc, acc[r][1], g1), 0.0f);
        }
    } else {
        // ---- general path: full iteration loop (correct; never taken) -------
        const float dinv0 = 1.0f / (LBD2_ + Mc[(p0 + 0) * OUT_ + (p0 + 0)]);
        const float dinv1 = 1.0f / (LBD2_ + Mc[(p0 + 1) * OUT_ + (p0 + 1)]);
        float wxb[2][2];
        #pragma unroll
        for (int r = 0; r < 2; ++r) {
            wxb[r][0] = acc[r][0] - bv2.x;
            wxb[r][1] = acc[r][1] - bv2.y;
            y[r][0] = 0.f; y[r][1] = 0.f;
        }
        float* Ylds = smem;   // 8 x 128
        for (int it = 0; it < MAXITER_; ++it) {
            float dt = fmaxf(0.05f / (1.0f + (float)it / 10.0f), 0.01f);
            #pragma unroll
            for (int r = 0; r < 2; ++r) {
                Ylds[(wv * 2 + r) * OUT_ + p0 + 0] = y[r][0];
                Ylds[(wv * 2 + r) * OUT_ + p0 + 1] = y[r][1];
            }
            __syncthreads();
            float my[2][2] = {{0.f, 0.f}, {0.f, 0.f}};
            for (int o = 0; o < OUT_; ++o) {
                float m0 = Mc[(p0 + 0) * OUT_ + o] - (o == p0 + 0 ? 1.0f : 0.0f);
                float m1 = Mc[(p0 + 1) * OUT_ + o] - (o == p0 + 1 ? 1.0f : 0.0f);
                #pragma unroll
                for (int r = 0; r < 2; ++r) {
                    float yo = Ylds[(wv * 2 + r) * OUT_ + o];
                    my[r][0] = fmaf(yo, m0, my[r][0]);
                    my[r][1] = fmaf(yo, m1, my[r][1]);
                }
            }
            #pragma unroll
            for (int r = 0; r < 2; ++r) {
                float uy0 = fmaf(dt, wxb[r][0] - y[r][0] - my[r][0], y[r][0]);
                float uy1 = fmaf(dt, wxb[r][1] - y[r][1] - my[r][1], y[r][1]);
                y[r][0] = fmaxf((uy0 - LBD1_) * dinv0, 0.0f);
                y[r][1] = fmaxf((uy1 - LBD1_) * dinv1, 0.0f);
            }
            __syncthreads();
        }
    }

    // ---- store Y: out[c][b][o], lanes cover 128 contiguous cols -------------
    #pragma unroll
    for (int r = 0; r < 2; ++r) {
        float2 s = {y[r][0], y[r][1]};
        *(float2*)(out + (c * B_ + row0 + r) * OUT_ + p0) = s;
    }
}

extern "C" void kernel_launch(void* const* d_in, const int* in_sizes, int n_in,
                              void* d_out, int out_size, void* d_ws, size_t ws_size,
                              hipStream_t stream)
{
    const float* X  = (const float*)d_in[0];   // [B, IN]
    const float* W  = (const float*)d_in[1];   // [C, OUT, IN]
    const float* M  = (const float*)d_in[2];   // [C, OUT, OUT]
    const float* bv = (const float*)d_in[3];   // [C, OUT]
    // d_in[4] = errTrack: unused (loop provably never converges early)
    float* out = (float*)d_out;                // [C, B, OUT]

    // Closed-form constants for the M==I fast path (fp32 dt schedule, double agg).
    const double dinv = 1.0 / (double)(1.0f + LBD2_);   // 1/1.005
    double P = 0.0, Q = 0.0;
    for (int n = 0; n < MAXITER_; ++n) {
        float dtf = fmaxf(0.05f / (1.0f + (float)n / 10.0f), 0.01f);
        double dt = (double)dtf;
        double A  = (1.0 - dt) * dinv;
        P = A * P + dinv * dt;
        Q = A * Q - dinv * (double)LBD1_;
    }

    const int blocks = C_ * (B_ / ROWS_PER_BLOCK_);   // 1024, 4 per CU resident
    pcn_kernel<<<blocks, THREADS_, 0, stream>>>(X, W, M, bv, out,
                                                (float)P, (float)Q);
}

// Round 5
// 68.722 us; speedup vs baseline: 1.1170x; 1.1170x over previous
//
#include <hip/hip_runtime.h>
#include <math.h>

// PlaceCellNetwork: C=4, B=2048, IN=64, OUT=128, 100 fixed-point iterations.
//
// With M == I (the actual input, verified EXACTLY via bitwise check), the
// iteration collapses in closed form (round-2 derivation, clamp-monotone):
//   y_final = max(P_100*wx + Q_100 - P_100*b, 0)   exactly.
//
// Round-5: kernel is total-issue-bound at depressed clock (~545 MHz measured
// via round-1->2 delta). Move the 512 fma/thread Wx onto the idle MFMA pipe:
//   mfma_f32_16x16x32_bf16 with 2-term Dekker split (hi=trunc bf16, lo=x-hi),
//   3 products (hi*hi + hi*lo + lo*hi), dropped lo*lo ~ 2^-16 rel.
// A = X[m][k], B = W[n][k] -- both native layouts -> NO LDS staging at all.
// Verified layouts (learn_hip m89/m91/m120): A[m=lane&15][k=(lane>>4)*8+j],
// B[n=lane&15][k=(lane>>4)*8+j], D col=lane&15, row=(lane>>4)*4+reg.

#define C_ 4
#define IN_ 64
#define OUT_ 128
#define B_ 2048
#define MAXITER_ 100
#define LBD1_ 0.005f
#define LBD2_ 0.005f

#define THREADS_ 256
#define ROWS_PER_BLOCK_ 16   // one 16-row M-tile per block; 4 waves x 32 cols

typedef short bf16x8 __attribute__((ext_vector_type(8)));   // 8 bf16 bit-patterns
typedef float f32x4  __attribute__((ext_vector_type(4)));

struct Frag2 { bf16x8 hi, lo; };

// Split 8 consecutive fp32 into (hi, lo) bf16x8 fragments.
// hi = truncate-to-bf16(x); lo = truncate-to-bf16(x - hi)  (x - hi is exact).
__device__ inline Frag2 split8(float4 a, float4 b)
{
    float xs[8] = {a.x, a.y, a.z, a.w, b.x, b.y, b.z, b.w};
    union { unsigned u[4]; bf16x8 v; } H, L;
    #pragma unroll
    for (int d = 0; d < 4; ++d) {
        float x0 = xs[2 * d], x1 = xs[2 * d + 1];
        unsigned u0 = __float_as_uint(x0), u1 = __float_as_uint(x1);
        float h0 = __uint_as_float(u0 & 0xFFFF0000u);
        float h1 = __uint_as_float(u1 & 0xFFFF0000u);
        float l0 = x0 - h0;
        float l1 = x1 - h1;
        // pack top halves of (u0,u1) -> one dword (low16 from u0)
        H.u[d] = __builtin_amdgcn_perm(u1, u0, 0x07060302u);
        L.u[d] = __builtin_amdgcn_perm(__float_as_uint(l1), __float_as_uint(l0),
                                       0x07060302u);
    }
    Frag2 f; f.hi = H.v; f.lo = L.v; return f;
}

__global__ __launch_bounds__(THREADS_)
void pcn_kernel(const float* __restrict__ X,
                const float* __restrict__ W,
                const float* __restrict__ M,
                const float* __restrict__ bvec,
                float* __restrict__ out,
                float Pc, float Qc)
{
    __shared__ float Ylds[ROWS_PER_BLOCK_ * OUT_];   // general path only (8 KB)
    __shared__ unsigned red[4];

    const int tid   = threadIdx.x;
    const int bx    = blockIdx.x;
    const int c     = bx >> 7;          // 128 chunks per c
    const int chunk = bx & 127;
    const int wv    = tid >> 6;         // wave 0..3
    const int lane  = tid & 63;
    const int ln16  = lane & 15;        // m-index for A, n-index for B/D-col
    const int q     = lane >> 4;        // quad 0..3
    const int ob    = 32 * wv;          // wave's output-column base
    const int row0  = chunk * ROWS_PER_BLOCK_;

    const float* Wc = W + c * (OUT_ * IN_);
    const float* Mc = M + c * (OUT_ * OUT_);

    // ---- raw fragment loads (issued first; all native-layout global) -------
    //  A: X[row0+ln16][q*8 + kk*32 + 0..7]   (2 kk-chunks x 2 float4)
    //  B: W[ob+16t+ln16][q*8 + kk*32 + 0..7] (2 tiles x 2 kk x 2 float4)
    const float* Xr = X + (row0 + ln16) * IN_ + q * 8;
    float4 ax[2][2], bw[2][2][2];
    #pragma unroll
    for (int kk = 0; kk < 2; ++kk) {
        ax[kk][0] = *(const float4*)(Xr + 32 * kk);
        ax[kk][1] = *(const float4*)(Xr + 32 * kk + 4);
    }
    #pragma unroll
    for (int t = 0; t < 2; ++t) {
        const float* Wr = Wc + (ob + 16 * t + ln16) * IN_ + q * 8;
        #pragma unroll
        for (int kk = 0; kk < 2; ++kk) {
            bw[t][kk][0] = *(const float4*)(Wr + 32 * kk);
            bw[t][kk][1] = *(const float4*)(Wr + 32 * kk + 4);
        }
    }

    // ---- bitwise M == I check over this thread's 64-entry segment ----------
    unsigned bad = 0;
    {
        const int row     = tid >> 1;
        const int colbase = (tid & 1) * 64;
        const int dIdx    = row - colbase;
        const uint4* mrow = (const uint4*)(Mc + row * OUT_ + colbase);
        #pragma unroll
        for (int j4 = 0; j4 < 16; ++j4) {
            uint4 v = mrow[j4];
            int e = dIdx - 4 * j4;
            bad |= v.x ^ ((e == 0) ? 0x3F800000u : 0u);
            bad |= v.y ^ ((e == 1) ? 0x3F800000u : 0u);
            bad |= v.z ^ ((e == 2) ? 0x3F800000u : 0u);
            bad |= v.w ^ ((e == 3) ? 0x3F800000u : 0u);
        }
    }

    // ---- split to bf16 hi/lo fragments -------------------------------------
    Frag2 Af[2];
    #pragma unroll
    for (int kk = 0; kk < 2; ++kk) Af[kk] = split8(ax[kk][0], ax[kk][1]);
    Frag2 Bf[2][2];
    #pragma unroll
    for (int t = 0; t < 2; ++t)
        #pragma unroll
        for (int kk = 0; kk < 2; ++kk)
            Bf[t][kk] = split8(bw[t][kk][0], bw[t][kk][1]);

    // ---- MFMA: wx tiles (hi*hi + hi*lo + lo*hi) ----------------------------
    f32x4 acc[2];
    acc[0] = (f32x4){0.f, 0.f, 0.f, 0.f};
    acc[1] = (f32x4){0.f, 0.f, 0.f, 0.f};
    #pragma unroll
    for (int t = 0; t < 2; ++t) {
        #pragma unroll
        for (int kk = 0; kk < 2; ++kk) {
            acc[t] = __builtin_amdgcn_mfma_f32_16x16x32_bf16(
                         Af[kk].hi, Bf[t][kk].hi, acc[t], 0, 0, 0);
            acc[t] = __builtin_amdgcn_mfma_f32_16x16x32_bf16(
                         Af[kk].hi, Bf[t][kk].lo, acc[t], 0, 0, 0);
            acc[t] = __builtin_amdgcn_mfma_f32_16x16x32_bf16(
                         Af[kk].lo, Bf[t][kk].hi, acc[t], 0, 0, 0);
        }
    }

    // ---- reduce M check -> block flag --------------------------------------
    #pragma unroll
    for (int off = 32; off > 0; off >>= 1)
        bad |= __shfl_down(bad, off);
    if (lane == 0) red[wv] = bad;
    __syncthreads();
    const bool m_ident = ((red[0] | red[1] | red[2] | red[3]) == 0u);

    // ---- per-column bias constants (n = ln16 per tile) ---------------------
    float gb[2], bt[2];
    #pragma unroll
    for (int t = 0; t < 2; ++t) {
        bt[t] = bvec[c * OUT_ + ob + 16 * t + ln16];
        gb[t] = fmaf(-Pc, bt[t], Qc);     // Qc - Pc*b
    }

    if (m_ident) {
        // ---- closed form: y = max(P*wx + (Q - P*b), 0), D-layout store -----
        #pragma unroll
        for (int t = 0; t < 2; ++t) {
            #pragma unroll
            for (int r = 0; r < 4; ++r) {
                int m = q * 4 + r;                    // output row within tile
                float y = fmaxf(fmaf(Pc, acc[t][r], gb[t]), 0.0f);
                out[(c * B_ + row0 + m) * OUT_ + ob + 16 * t + ln16] = y;
            }
        }
    } else {
        // ---- general path: full iteration loop (correct; never taken) ------
        int   nt[2];
        float dinvv[2];
        #pragma unroll
        for (int t = 0; t < 2; ++t) {
            nt[t]    = ob + 16 * t + ln16;
            dinvv[t] = 1.0f / (LBD2_ + Mc[nt[t] * OUT_ + nt[t]]);
        }
        float wxb[2][4], y[2][4];
        #pragma unroll
        for (int t = 0; t < 2; ++t)
            #pragma unroll
            for (int r = 0; r < 4; ++r) {
                wxb[t][r] = acc[t][r] - bt[t];
                y[t][r] = 0.f;
            }
        for (int it = 0; it < MAXITER_; ++it) {
            float dt = fmaxf(0.05f / (1.0f + (float)it / 10.0f), 0.01f);
            #pragma unroll
            for (int t = 0; t < 2; ++t)
                #pragma unroll
                for (int r = 0; r < 4; ++r)
                    Ylds[(q * 4 + r) * OUT_ + nt[t]] = y[t][r];
            __syncthreads();
            float my[2][4] = {{0.f,0.f,0.f,0.f},{0.f,0.f,0.f,0.f}};
            for (int o = 0; o < OUT_; ++o) {
                float mo[2];
                #pragma unroll
                for (int t = 0; t < 2; ++t)
                    mo[t] = Mc[nt[t] * OUT_ + o] - (o == nt[t] ? 1.0f : 0.0f);
                #pragma unroll
                for (int r = 0; r < 4; ++r) {
                    float yo = Ylds[(q * 4 + r) * OUT_ + o];
                    my[0][r] = fmaf(yo, mo[0], my[0][r]);
                    my[1][r] = fmaf(yo, mo[1], my[1][r]);
                }
            }
            #pragma unroll
            for (int t = 0; t < 2; ++t)
                #pragma unroll
                for (int r = 0; r < 4; ++r) {
                    float uy = fmaf(dt, wxb[t][r] - y[t][r] - my[t][r], y[t][r]);
                    y[t][r] = fmaxf((uy - LBD1_) * dinvv[t], 0.0f);
                }
            __syncthreads();
        }
        #pragma unroll
        for (int t = 0; t < 2; ++t)
            #pragma unroll
            for (int r = 0; r < 4; ++r)
                out[(c * B_ + row0 + q * 4 + r) * OUT_ + nt[t]] = y[t][r];
    }
}

extern "C" void kernel_launch(void* const* d_in, const int* in_sizes, int n_in,
                              void* d_out, int out_size, void* d_ws, size_t ws_size,
                              hipStream_t stream)
{
    const float* X  = (const float*)d_in[0];   // [B, IN]
    const float* W  = (const float*)d_in[1];   // [C, OUT, IN]
    const float* M  = (const float*)d_in[2];   // [C, OUT, OUT]
    const float* bv = (const float*)d_in[3];   // [C, OUT]
    // d_in[4] = errTrack: unused (loop provably never converges early)
    float* out = (float*)d_out;                // [C, B, OUT]

    // Closed-form constants for the M==I fast path (fp32 dt schedule, double agg).
    const double dinv = 1.0 / (double)(1.0f + LBD2_);   // 1/1.005
    double P = 0.0, Q = 0.0;
    for (int n = 0; n < MAXITER_; ++n) {
        float dtf = fmaxf(0.05f / (1.0f + (float)n / 10.0f), 0.01f);
        double dt = (double)dtf;
        double A  = (1.0 - dt) * dinv;
        P = A * P + dinv * dt;
        Q = A * Q - dinv * (double)LBD1_;
    }

    const int blocks = C_ * (B_ / ROWS_PER_BLOCK_);   // 512, 2 per CU
    pcn_kernel<<<blocks, THREADS_, 0, stream>>>(X, W, M, bv, out,
                                                (float)P, (float)Q);
}